// Round 12
// baseline (483.616 us; speedup 1.0000x reference)
//
#include <hip/hip_runtime.h>

// RepetHead: 4 layers of (3x3 offset conv -> DCNv1 deform conv -> ReLU)
// B=4, C=256, H=W=64, K=9 taps.
// Round 18: 4-chunk super-bodies -- 18 barriers/block (was 36), 8 x 8KB
// LDS sub-buffers (smem 88.6KB, still 1 block/CU by grid=256). Per super:
// 4 combines -> ONE lgkm barrier -> 8 ds_read + 32-MFMA cluster/wave.
// Continues R11's barrier-halving curve (72->36 was +9%). Accumulation
// order per wave unchanged (kv, kv+2, kv+4, kv+6 per tap) -> bitwise
// identical. Single G-set prefetch 1 super ahead (~9000 cyc distance,
// same absolute as R16). Prep kernels reverted to measured-best R16.
// Falsified so far: VALU tput (R7), bank conflicts (R9/R15), vmcnt drain
// (R10), L2 traffic (R13/R15), LDS read BW (R15), gather latency (R16),
// head pipelining (R17). Residual theory: barrier-window convoy stall.
//
// ws layout (floats):
//   (294,912 floats reserved, unused since R12)
//   wph  : 1,179,648  (2,359,296 ushort, deform B frag-packed, bf16-hi)
//   owph :   147,456  (  294,912 ushort, offset-conv B frag-packed)
//   xTA  : 2,097,152  (4,194,304 ushort, plane ping)
//   xTB  : 2,097,152  (4,194,304 ushort, plane pong)

#define HW 4096

typedef __attribute__((ext_vector_type(8))) __bf16 bf16x8;
typedef __attribute__((ext_vector_type(4))) float f32x4;
typedef __attribute__((ext_vector_type(8))) unsigned short u16x8;

__device__ inline unsigned int f2bf_bits(float f) {
  unsigned int u = __float_as_uint(f);
  return (u + 0x7fffu + ((u >> 16) & 1u)) >> 16;   // RNE to bf16
}

// Workgroup barrier with LDS-only ordering: no vmcnt drain, so global
// prefetches stay in flight across it. sched_barrier pins ds_read motion.
__device__ inline void wg_barrier_lds() {
  asm volatile("s_waitcnt lgkmcnt(0)" ::: "memory");
  __builtin_amdgcn_s_barrier();
  __builtin_amdgcn_sched_barrier(0);
}

// ---------------------------------------------------------------------------
// w[r][o][c][ky][kx] -> frag-packed wph[r][q=72][nt=16][lane=64][j=8] (bf16-hi)
// n = nt*16+(lane&15); kk = q*32+(lane>>4)*8+j; c = kk&255; k = kk>>8.
__global__ __launch_bounds__(256) void wpack_kernel(
    const float* __restrict__ w, unsigned short* __restrict__ wph) {
  const int f = blockIdx.x * 256 + threadIdx.x;   // < 2,359,296
  const int j  = f & 7;
  const int l  = (f >> 3) & 63;
  const int nt = (f >> 9) & 15;
  const int q  = (f >> 13) % 72;
  const int r  = f / 589824;
  const int n  = nt * 16 + (l & 15);
  const int kk = q * 32 + ((l >> 4) << 3) + j;
  const int c  = kk & 255, k = kk >> 8;
  wph[f] = (unsigned short)f2bf_bits(w[((r * 256 + n) * 256 + c) * 9 + k]);
}

// offw[r][18][256][3][3] -> owph[r][q=72][nt=2][lane=64][j=8] (n>=18 -> 0)
__global__ __launch_bounds__(256) void offwpack_kernel(
    const float* __restrict__ offw, unsigned short* __restrict__ owph) {
  const int f = blockIdx.x * 256 + threadIdx.x;   // < 294,912
  const int j  = f & 7;
  const int l  = (f >> 3) & 63;
  const int nt = (f >> 9) & 1;
  const int q  = (f >> 10) % 72;
  const int r  = f / 73728;
  const int n  = nt * 16 + (l & 15);
  const int kk = q * 32 + ((l >> 4) << 3) + j;
  const int c  = kk & 255, k = kk >> 8;
  const float v = (n < 18) ? offw[((r * 18 + n) * 256 + c) * 9 + k] : 0.f;
  owph[f] = (unsigned short)f2bf_bits(v);
}

// ---------------------------------------------------------------------------
// x [4][256][4096] fp32 -> xT [4][4096][256] bf16-hi (transpose + cast)
__global__ __launch_bounds__(256) void xpose_kernel(
    const float* __restrict__ x, unsigned short* __restrict__ xh) {
  const int p0 = blockIdx.x * 64;     // pos tile
  const int c0 = blockIdx.y * 64;     // channel tile
  const int b  = blockIdx.z;
  __shared__ float sT[64][65];
  const int t = threadIdx.x;
  const int pj = t & 63, ci0 = (t >> 6) * 16;
  const float* __restrict__ xb = x + ((size_t)(b * 256 + c0)) * HW + p0;
#pragma unroll
  for (int u = 0; u < 16; ++u)
    sT[ci0 + u][pj] = xb[(size_t)(ci0 + u) * HW + pj];
  __syncthreads();
  const int pr = t >> 2, cs = (t & 3) * 16;
  u16x8 va, vb;
#pragma unroll
  for (int u = 0; u < 8; ++u) va[u] = (unsigned short)f2bf_bits(sT[cs + u][pr]);
#pragma unroll
  for (int u = 0; u < 8; ++u) vb[u] = (unsigned short)f2bf_bits(sT[cs + 8 + u][pr]);
  const size_t o = ((size_t)b * HW + p0 + pr) * 256 + c0 + cs;
  *(u16x8*)(xh + o) = va;
  *(u16x8*)(xh + o + 8) = vb;
}

// ---------------------------------------------------------------------------
// FUSED: offset-conv head + bilinear-sample + bf16 MFMA GEMM + ReLU.
// Block: M=64 (full row h), N=256, 1024 threads = 16 waves, grid 256
// (1 block/CU). Head: (mtO,ntO,kv)=(wv&3,(wv>>2)&1,wv>>3).
// Main loop waves: kv = wv>>3 (chunk parity), wmh = (wv>>2)&1 (32-row
// half), wng = wv&3 (64-col group). 4-chunk supers (18 barriers), 8 x 8KB
// sub-buffers; per super per wave: 8 ds_read_b128, 32 MFMAs (chunks kv
// then kv+2 -- order identical to R16's two 2-chunk supers).
__global__ __launch_bounds__(1024, 4) void deform_mfma(
    const unsigned short* __restrict__ xh,   // [4][4096][256] bf16-hi plane
    const unsigned short* __restrict__ owh,  // offset B frags, this layer
    const float* __restrict__ offb,          // bias[18], this layer
    const unsigned short* __restrict__ wph,  // [72][16][64][8] this layer
    unsigned short* __restrict__ yth,        // next plane (layers 0-2)
    float* __restrict__ outf) {              // fp32 NCHW out (layer 3)
  const int gid = blockIdx.x;                  // 0..255
  const int b = (gid & 7) >> 1;                // 2 XCDs per batch image
  const int h = ((gid >> 3) << 1) | (gid & 1);     // full row 0..63
  const int t = threadIdx.x, lane = t & 63, wv = t >> 6;   // 16 waves
  const int frow = lane & 15, quad = lane >> 4;
  const int sm = t >> 4, cg = t & 15;          // staging: row 0..63, pair 0..15

  __shared__ __align__(16) unsigned char smem[88576];
  float* s_cw = (float*)smem;                  // [9][4][64] = 9216 B
  int*   s_ci = (int*)(smem + 9216);           // [9][4][64] = 9216 B
  unsigned char* sAb = smem + 18432;           // 8 sub-bufs x 8192 B
  float* s_off = (float*)(smem + 83968);       // [18][64] = 4608 B

  // ======== offset-conv head: this block's 18x64 offsets -> s_off ========
  {
    const int kv = wv >> 3, ntO = (wv >> 2) & 1, mtO = wv & 3;
    const int mO = mtO * 16 + frow;            // w coordinate of A row
    f32x4 aoc = {0.f, 0.f, 0.f, 0.f};
    const u16x8 z8 = {};
    const size_t xb = (size_t)b * HW;
    const u16x8* __restrict__ owp = (const u16x8*)owh;

#define OHLOAD(k, p, A, Bv)                                                 \
  {                                                                         \
    const int ky = (k) / 3 - 1, kx = (k) % 3 - 1;                           \
    const int hy = h + ky;                                                  \
    const int hyc = hy < 0 ? 0 : (hy > 63 ? 63 : hy);                       \
    const int mx = mO + kx;                                                 \
    const bool v = ((unsigned)hy < 64u) && ((unsigned)mx < 64u);            \
    const int cpx = mx < 0 ? 0 : (mx > 63 ? 63 : mx);                       \
    const size_t abase = (xb + (size_t)(hyc * 64 + cpx)) * 256              \
                         + quad * 8 + kv * 128 + (p) * 64;                  \
    _Pragma("unroll") for (int j = 0; j < 2; ++j) {                         \
      A[j] = *(const u16x8*)(xh + abase + j * 32);                          \
      if (!v) A[j] = z8;                                                    \
    }                                                                       \
    _Pragma("unroll") for (int j = 0; j < 2; ++j)                           \
      Bv[j] = owp[(((k) * 8 + kv * 4 + (p) * 2 + j) * 2 + ntO) * 64 + lane];\
  }

#define OHMFMA(A, Bv)                                                       \
  _Pragma("unroll") for (int j = 0; j < 2; ++j)                             \
    aoc = __builtin_amdgcn_mfma_f32_16x16x32_bf16(                          \
        __builtin_bit_cast(bf16x8, A[j]), __builtin_bit_cast(bf16x8, Bv[j]),\
        aoc, 0, 0, 0);

    u16x8 A0[2], Bv0[2], A1[2], Bv1[2];
    OHLOAD(0, 0, A0, Bv0)
    OHLOAD(0, 1, A1, Bv1)
    OHMFMA(A0, Bv0) OHLOAD(1, 0, A0, Bv0)
    OHMFMA(A1, Bv1) OHLOAD(1, 1, A1, Bv1)
    OHMFMA(A0, Bv0) OHLOAD(2, 0, A0, Bv0)
    OHMFMA(A1, Bv1) OHLOAD(2, 1, A1, Bv1)
    OHMFMA(A0, Bv0) OHLOAD(3, 0, A0, Bv0)
    OHMFMA(A1, Bv1) OHLOAD(3, 1, A1, Bv1)
    OHMFMA(A0, Bv0) OHLOAD(4, 0, A0, Bv0)
    OHMFMA(A1, Bv1) OHLOAD(4, 1, A1, Bv1)
    OHMFMA(A0, Bv0) OHLOAD(5, 0, A0, Bv0)
    OHMFMA(A1, Bv1) OHLOAD(5, 1, A1, Bv1)
    OHMFMA(A0, Bv0) OHLOAD(6, 0, A0, Bv0)
    OHMFMA(A1, Bv1) OHLOAD(6, 1, A1, Bv1)
    OHMFMA(A0, Bv0) OHLOAD(7, 0, A0, Bv0)
    OHMFMA(A1, Bv1) OHLOAD(7, 1, A1, Bv1)
    OHMFMA(A0, Bv0) OHLOAD(8, 0, A0, Bv0)
    OHMFMA(A1, Bv1) OHLOAD(8, 1, A1, Bv1)
    OHMFMA(A0, Bv0)
    OHMFMA(A1, Bv1)
#undef OHLOAD
#undef OHMFMA

    f32x4* redp = (f32x4*)(smem + 18432);      // transient, pre-main-loop
    if (kv == 1) redp[(mtO * 2 + ntO) * 64 + lane] = aoc;
    __syncthreads();
    if (kv == 0) {
      const f32x4 o = redp[(mtO * 2 + ntO) * 64 + lane];
      aoc[0] += o[0]; aoc[1] += o[1]; aoc[2] += o[2]; aoc[3] += o[3];
      const int oc = ntO * 16 + frow;          // C/D: col = lane&15 -> n
      if (oc < 18) {
        const float bv = offb[oc];
        const int mb = mtO * 16 + quad * 4;    // C/D row = (lane>>4)*4 + r
#pragma unroll
        for (int r = 0; r < 4; ++r) s_off[oc * 64 + mb + r] = aoc[r] + bv;
      }
    }
    __syncthreads();
  }

  // ======== phase 0: per (k, m) bilinear setup from s_off ========
  if (t < 576) {
    const int k = t >> 6, m = t & 63;
    const int ky = k / 3 - 1, kx = k % 3 - 1;
    const float dy = s_off[(2 * k) * 64 + m];
    const float dx = s_off[(2 * k + 1) * 64 + m];
    const float py = (float)(h + ky) + dy;
    const float px = (float)(m + kx) + dx;
    const float y0f = floorf(py), x0f = floorf(px);
    const float wy = py - y0f, wx = px - x0f;
    const int y0 = (int)y0f, x0 = (int)x0f;
#pragma unroll
    for (int j = 0; j < 4; ++j) {
      const int yi = y0 + (j >> 1), xi = x0 + (j & 1);
      const bool v = (yi >= 0) && (yi < 64) && (xi >= 0) && (xi < 64);
      const float wgt = ((j >> 1) ? wy : 1.f - wy) * ((j & 1) ? wx : 1.f - wx);
      s_cw[(k * 4 + j) * 64 + m] = v ? wgt : 0.f;
      const int yc = yi < 0 ? 0 : (yi > 63 ? 63 : yi);
      const int xc = xi < 0 ? 0 : (xi > 63 ? 63 : xi);
      s_ci[(k * 4 + j) * 64 + m] = yc * 64 + xc;
    }
  }
  __syncthreads();

  f32x4 acc[2][4];                             // 2 m-tiles x 4 n-tiles
#pragma unroll
  for (int mt = 0; mt < 2; ++mt)
#pragma unroll
    for (int nt = 0; nt < 4; ++nt) acc[mt][nt] = (f32x4){0.f, 0.f, 0.f, 0.f};

  const char* __restrict__ xbc = (const char*)(xh + (size_t)b * HW * 256);
  const u16x8* __restrict__ wp = (const u16x8*)wph;
  const int kv  = wv >> 3;                     // chunk parity (0=even,1=odd)
  const int wmh = (wv >> 2) & 1;               // m-half (32 rows)
  const int wng = wv & 3;                      // n-group (4 n-tiles)
  const int bfo = wng * 4;                     // wave's n-tile base

  // XOR-swizzled staging addresses (loop-invariant, per 8KB sub-buffer).
  const int gs = ((sm & 3) << 1) | ((sm >> 2) & 1);
  const int wbA = sm * 128 + ((((cg >> 2) ^ gs)) << 4) + (cg & 3) * 4;  // hi
  const int wbL = wbA ^ 64;                                            // lo
  const int gr = ((frow & 3) << 1) | ((frow >> 2) & 1);
  const int rbM = (wmh * 32 + frow) * 128 + ((quad ^ gr) << 4);
  const int rcA = kv * 8192;                   // wave's 1st parity chunk
  const int rcB = rcA + 16384;                 // wave's 2nd parity chunk

  unsigned int G0[4], G1[4], G2[4], G3[4];
  u16x8 Bc[4], Bd[4];
  float cwrC[4], cwrN[4];
  int cibC[4], cibN[4];
#pragma unroll
  for (int j = 0; j < 4; ++j) {   // tap 0 staging params (byte offsets)
    cwrC[j] = s_cw[j * 64 + sm];
    cibC[j] = s_ci[j * 64 + sm] * 512;
  }
#pragma unroll
  for (int j = 0; j < 4; ++j)     // tap 0 chunks 0-3
    G0[j] = *(const unsigned int*)(xbc + cibC[j] + cg * 4);
#pragma unroll
  for (int j = 0; j < 4; ++j)
    G1[j] = *(const unsigned int*)(xbc + cibC[j] + 64 + cg * 4);
#pragma unroll
  for (int j = 0; j < 4; ++j)
    G2[j] = *(const unsigned int*)(xbc + cibC[j] + 128 + cg * 4);
#pragma unroll
  for (int j = 0; j < 4; ++j)
    G3[j] = *(const unsigned int*)(xbc + cibC[j] + 192 + cg * 4);
#pragma unroll
  for (int i = 0; i < 4; ++i)     // B frags: tap0 chunks kv, kv+2
    Bc[i] = wp[(kv * 16 + bfo + i) * 64 + lane];
#pragma unroll
  for (int i = 0; i < 4; ++i)
    Bd[i] = wp[((2 + kv) * 16 + bfo + i) * 64 + lane];

#define COMBINE_STORE(Gx, BB)                                               \
  {                                                                         \
    float s0 = cwrC[0] * __uint_as_float(Gx[0] << 16);                      \
    float s1 = cwrC[0] * __uint_as_float(Gx[0] & 0xffff0000u);              \
    s0 = fmaf(cwrC[1], __uint_as_float(Gx[1] << 16), s0);                   \
    s1 = fmaf(cwrC[1], __uint_as_float(Gx[1] & 0xffff0000u), s1);           \
    s0 = fmaf(cwrC[2], __uint_as_float(Gx[2] << 16), s0);                   \
    s1 = fmaf(cwrC[2], __uint_as_float(Gx[2] & 0xffff0000u), s1);           \
    s0 = fmaf(cwrC[3], __uint_as_float(Gx[3] << 16), s0);                   \
    s1 = fmaf(cwrC[3], __uint_as_float(Gx[3] & 0xffff0000u), s1);           \
    const __bf16 hb0 = (__bf16)s0, hb1 = (__bf16)s1;                        \
    const unsigned int hv =                                                 \
        (unsigned int)__builtin_bit_cast(unsigned short, hb0) |             \
        ((unsigned int)__builtin_bit_cast(unsigned short, hb1) << 16);      \
    const float d0 = s0 - __uint_as_float(hv << 16);                        \
    const float d1 = s1 - __uint_as_float(hv & 0xffff0000u);                \
    const __bf16 lb0 = (__bf16)d0, lb1 = (__bf16)d1;                        \
    const unsigned int lv =                                                 \
        (unsigned int)__builtin_bit_cast(unsigned short, lb0) |             \
        ((unsigned int)__builtin_bit_cast(unsigned short, lb1) << 16);      \
    *(unsigned int*)(sAb + (BB) + wbA) = hv;                                \
    *(unsigned int*)(sAb + (BB) + wbL) = lv;                                \
  }

// One super per wave: chunks kv then kv+2 of half HB, 8 ds_read, 32 MFMA.
// Accumulation order identical to two consecutive 2-chunk supers.
#define MFMA_BODY4(HB)                                                      \
  {                                                                         \
    bf16x8 ah0[2], al0[2], ah1[2], al1[2];                                  \
    ah0[0] = __builtin_bit_cast(                                            \
        bf16x8, *(const u16x8*)(sAb + (HB) + rcA + rbM));                   \
    al0[0] = __builtin_bit_cast(                                            \
        bf16x8, *(const u16x8*)(sAb + (HB) + rcA + (rbM ^ 64)));            \
    ah0[1] = __builtin_bit_cast(                                            \
        bf16x8, *(const u16x8*)(sAb + (HB) + rcA + rbM + 2048));            \
    al0[1] = __builtin_bit_cast(                                            \
        bf16x8, *(const u16x8*)(sAb + (HB) + rcA + ((rbM + 2048) ^ 64)));   \
    ah1[0] = __builtin_bit_cast(                                            \
        bf16x8, *(const u16x8*)(sAb + (HB) + rcB + rbM));                   \
    al1[0] = __builtin_bit_cast(                                            \
        bf16x8, *(const u16x8*)(sAb + (HB) + rcB + (rbM ^ 64)));            \
    ah1[1] = __builtin_bit_cast(                                            \
        bf16x8, *(const u16x8*)(sAb + (HB) + rcB + rbM + 2048));            \
    al1[1] = __builtin_bit_cast(                                            \
        bf16x8, *(const u16x8*)(sAb + (HB) + rcB + ((rbM + 2048) ^ 64)));   \
    __builtin_amdgcn_s_setprio(1);                                          \
    _Pragma("unroll") for (int nt = 0; nt < 4; ++nt) {                      \
      const bf16x8 bv = __builtin_bit_cast(bf16x8, Bc[nt]);                 \
      _Pragma("unroll") for (int mt = 0; mt < 2; ++mt) {                    \
        acc[mt][nt] = __builtin_amdgcn_mfma_f32_16x16x32_bf16(              \
            ah0[mt], bv, acc[mt][nt], 0, 0, 0);                             \
        acc[mt][nt] = __builtin_amdgcn_mfma_f32_16x16x32_bf16(              \
            al0[mt], bv, acc[mt][nt], 0, 0, 0);                             \
      }                                                                     \
    }                                                                       \
    _Pragma("unroll") for (int nt = 0; nt < 4; ++nt) {                      \
      const bf16x8 bv = __builtin_bit_cast(bf16x8, Bd[nt]);                 \
      _Pragma("unroll") for (int mt = 0; mt < 2; ++mt) {                    \
        acc[mt][nt] = __builtin_amdgcn_mfma_f32_16x16x32_bf16(              \
            ah1[mt], bv, acc[mt][nt], 0, 0, 0);                             \
        acc[mt][nt] = __builtin_amdgcn_mfma_f32_16x16x32_bf16(              \
            al1[mt], bv, acc[mt][nt], 0, 0, 0);                             \
      }                                                                     \
    }                                                                       \
    __builtin_amdgcn_s_setprio(0);                                          \
  }

#define BADV2(cb)                                                           \
  {                                                                         \
    _Pragma("unroll") for (int i = 0; i < 4; ++i)                           \
      Bc[i] = wp[(((cb) + kv) * 16 + bfo + i) * 64 + lane];                 \
    _Pragma("unroll") for (int i = 0; i < 4; ++i)                           \
      Bd[i] = wp[(((cb) + 2 + kv) * 16 + bfo + i) * 64 + lane];             \
  }

  for (int k9 = 0; k9 < 9; ++k9) {
    const bool tapN = (k9 < 8);
    // ---- super A: tap-k9 chunks 0-3 -> bufs 0-3; prefetch chunks 4-7 ----
    COMBINE_STORE(G0, 0)
    COMBINE_STORE(G1, 8192)
    COMBINE_STORE(G2, 16384)
    COMBINE_STORE(G3, 24576)
    wg_barrier_lds();
#pragma unroll
    for (int j = 0; j < 4; ++j)
      G0[j] = *(const unsigned int*)(xbc + cibC[j] + 256 + cg * 4);
#pragma unroll
    for (int j = 0; j < 4; ++j)
      G1[j] = *(const unsigned int*)(xbc + cibC[j] + 320 + cg * 4);
#pragma unroll
    for (int j = 0; j < 4; ++j)
      G2[j] = *(const unsigned int*)(xbc + cibC[j] + 384 + cg * 4);
#pragma unroll
    for (int j = 0; j < 4; ++j)
      G3[j] = *(const unsigned int*)(xbc + cibC[j] + 448 + cg * 4);
    MFMA_BODY4(0)
    BADV2(k9 * 8 + 4)
    // ---- super B: tap-k9 chunks 4-7 -> bufs 4-7; prefetch next tap 0-3 ----
    COMBINE_STORE(G0, 32768)
    COMBINE_STORE(G1, 40960)
    COMBINE_STORE(G2, 49152)
    COMBINE_STORE(G3, 57344)
    wg_barrier_lds();
    if (tapN) {
#pragma unroll
      for (int j = 0; j < 4; ++j) {
        cwrN[j] = s_cw[((k9 + 1) * 4 + j) * 64 + sm];
        cibN[j] = s_ci[((k9 + 1) * 4 + j) * 64 + sm] * 512;
      }
#pragma unroll
      for (int j = 0; j < 4; ++j)
        G0[j] = *(const unsigned int*)(xbc + cibN[j] + cg * 4);
#pragma unroll
      for (int j = 0; j < 4; ++j)
        G1[j] = *(const unsigned int*)(xbc + cibN[j] + 64 + cg * 4);
#pragma unroll
      for (int j = 0; j < 4; ++j)
        G2[j] = *(const unsigned int*)(xbc + cibN[j] + 128 + cg * 4);
#pragma unroll
      for (int j = 0; j < 4; ++j)
        G3[j] = *(const unsigned int*)(xbc + cibN[j] + 192 + cg * 4);
    }
    MFMA_BODY4(32768)
    if (tapN) {
      BADV2((k9 + 1) * 8)
#pragma unroll
      for (int j = 0; j < 4; ++j) { cwrC[j] = cwrN[j]; cibC[j] = cibN[j]; }
    }
  }
#undef COMBINE_STORE
#undef MFMA_BODY4
#undef BADV2

  // ======== cross-kv accumulator reduction (kv1 -> kv0), 2 phases ========
  __syncthreads();   // all K-loop LDS traffic done before sAb reuse
  {
    float* redb = (float*)sAb;                 // 8 waves x 64 lanes x 16 f
    const int rbase = ((wv & 7) * 64 + lane) * 16;
#pragma unroll
    for (int ph = 0; ph < 2; ++ph) {
      if (kv == 1) {
#pragma unroll
        for (int mt = 0; mt < 2; ++mt)
#pragma unroll
          for (int q2 = 0; q2 < 2; ++q2)
            *(f32x4*)&redb[rbase + (mt * 2 + q2) * 4] = acc[mt][ph * 2 + q2];
      }
      __syncthreads();
      if (kv == 0) {
#pragma unroll
        for (int mt = 0; mt < 2; ++mt)
#pragma unroll
          for (int q2 = 0; q2 < 2; ++q2) {
            const f32x4 o = *(const f32x4*)&redb[rbase + (mt * 2 + q2) * 4];
            acc[mt][ph * 2 + q2][0] += o[0];
            acc[mt][ph * 2 + q2][1] += o[1];
            acc[mt][ph * 2 + q2][2] += o[2];
            acc[mt][ph * 2 + q2][3] += o[3];
          }
      }
      __syncthreads();
    }
  }

  if (outf) {
    // final layer: ReLU + direct fp32 NCHW scatter (kv0 waves only)
    if (kv == 0) {
#pragma unroll
      for (int mt = 0; mt < 2; ++mt)
#pragma unroll
        for (int nt = 0; nt < 4; ++nt) {
          const int n = wng * 64 + nt * 16 + frow;
          const int pos = h * 64 + wmh * 32 + mt * 16 + quad * 4;
          float4 vv;
          vv.x = fmaxf(acc[mt][nt][0], 0.f);
          vv.y = fmaxf(acc[mt][nt][1], 0.f);
          vv.z = fmaxf(acc[mt][nt][2], 0.f);
          vv.w = fmaxf(acc[mt][nt][3], 0.f);
          *(float4*)&outf[(size_t)(b * 256 + n) * HW + pos] = vv;
        }
    }
  } else {
    // layers 0-2: ReLU + bf16-hi transposed plane, kv0 waves via LDS slice.
    // Per kv0 wave: 32 rows x 64 cols through sW [32][72] (no 2^k alias).
    unsigned short* sW = (unsigned short*)(smem + (wv & 7) * 4608);
    if (kv == 0) {
#pragma unroll
      for (int mt = 0; mt < 2; ++mt)
#pragma unroll
        for (int nt = 0; nt < 4; ++nt)
#pragma unroll
          for (int r = 0; r < 4; ++r)
            sW[(mt * 16 + quad * 4 + r) * 72 + nt * 16 + frow] =
                (unsigned short)f2bf_bits(fmaxf(acc[mt][nt][r], 0.f));
    }
    __syncthreads();
    if (kv == 0) {
      const int rowl = lane & 31, colh = lane >> 5;  // 32 rows x 2 col-chunks
      const int pos = h * 64 + wmh * 32 + rowl;
      unsigned short* __restrict__ yp =
          yth + ((size_t)b * HW + pos) * 256 + wng * 64 + colh * 32;
#pragma unroll
      for (int g = 0; g < 4; ++g)
        *(u16x8*)(yp + g * 8) = *(const u16x8*)&sW[rowl * 72 + colh * 32 + g * 8];
    }
  }
}

extern "C" void kernel_launch(void* const* d_in, const int* in_sizes, int n_in,
                              void* d_out, int out_size, void* d_ws, size_t ws_size,
                              hipStream_t stream) {
  const float* x0   = (const float*)d_in[0];  // [4][256][64][64]
  const float* offw = (const float*)d_in[1];  // [4][18][256][3][3]
  const float* offb = (const float*)d_in[2];  // [4][18]
  const float* w    = (const float*)d_in[3];  // [4][256][256][3][3]
  float* out = (float*)d_out;                 // [4][256][64][64]
  float* ws  = (float*)d_ws;

  unsigned short* wph  = (unsigned short*)(ws + 294912);    // 2,359,296 ushort
  unsigned short* owph = wph + 2359296;                     //   294,912 ushort
  unsigned short* xTA  = owph + 294912;                     // 4,194,304 ushort
  unsigned short* xTB  = xTA + 4194304;                     // 4,194,304 ushort

  wpack_kernel<<<9216, 256, 0, stream>>>(w, wph);
  offwpack_kernel<<<1152, 256, 0, stream>>>(offw, owph);
  xpose_kernel<<<dim3(64, 4, 4), 256, 0, stream>>>(x0, xTA);

  unsigned short* pin = xTA;
  unsigned short* pout = xTB;
  for (int r = 0; r < 4; ++r) {
    deform_mfma<<<256, 1024, 0, stream>>>(pin, owph + r * 73728,
                                          offb + r * 18,
                                          wph + (size_t)r * 589824,
                                          (r < 3) ? pout : nullptr,
                                          (r < 3) ? nullptr : out);
    unsigned short* tmp = pin; pin = pout; pout = tmp;
  }
}

// Round 13
// 311.959 us; speedup vs baseline: 1.5503x; 1.5503x over previous
//
#include <hip/hip_runtime.h>

// RepetHead: 4 layers of (3x3 offset conv -> DCNv1 deform conv -> ReLU)
// B=4, C=256, H=W=64, K=9 taps.
// Round 19: drop the lo half of the hi/lo double-bf16 A-operand.
// Precision audit: x and w are ALREADY single-bf16 (xh/wph store bf16-hi),
// so the lo path only preserved f32 precision of the combine output s --
// one of three equal-magnitude (~2^-9 rel) error sources. Removing it:
// MFMA/wave/super 16->8, ds_read 4->2, staging dwords 4->2, combine VALU
// -6/2vals. Layout reuses R16's PROVEN addresses: even chunk in former
// "hi" slots, odd chunk in former "lo" slots (^64) of one 8KB buffer;
// kv0 waves read rb, kv1 read rb^64. smem 55.8->39.4 KB.
// R18 lesson: 4-chunk supers spilled G-sets to scratch (WRITE 120MB).
// Falsified: VALU tput, bank conflicts, vmcnt drain, L2 traffic, LDS BW,
// gather latency, head pipelining, barrier width (R18, confounded).
//
// ws layout (floats):
//   (294,912 floats reserved, unused since R12)
//   wph  : 1,179,648  (2,359,296 ushort, deform B frag-packed, bf16-hi)
//   owph :   147,456  (  294,912 ushort, offset-conv B frag-packed)
//   xTA  : 2,097,152  (4,194,304 ushort, plane ping)
//   xTB  : 2,097,152  (4,194,304 ushort, plane pong)

#define HW 4096

typedef __attribute__((ext_vector_type(8))) __bf16 bf16x8;
typedef __attribute__((ext_vector_type(4))) float f32x4;
typedef __attribute__((ext_vector_type(8))) unsigned short u16x8;

__device__ inline unsigned int f2bf_bits(float f) {
  unsigned int u = __float_as_uint(f);
  return (u + 0x7fffu + ((u >> 16) & 1u)) >> 16;   // RNE to bf16
}

// Workgroup barrier with LDS-only ordering: no vmcnt drain, so global
// prefetches stay in flight across it. sched_barrier pins ds_read motion.
__device__ inline void wg_barrier_lds() {
  asm volatile("s_waitcnt lgkmcnt(0)" ::: "memory");
  __builtin_amdgcn_s_barrier();
  __builtin_amdgcn_sched_barrier(0);
}

// ---------------------------------------------------------------------------
// w[r][o][c][ky][kx] -> frag-packed wph[r][q=72][nt=16][lane=64][j=8] (bf16-hi)
// n = nt*16+(lane&15); kk = q*32+(lane>>4)*8+j; c = kk&255; k = kk>>8.
__global__ __launch_bounds__(256) void wpack_kernel(
    const float* __restrict__ w, unsigned short* __restrict__ wph) {
  const int f = blockIdx.x * 256 + threadIdx.x;   // < 2,359,296
  const int j  = f & 7;
  const int l  = (f >> 3) & 63;
  const int nt = (f >> 9) & 15;
  const int q  = (f >> 13) % 72;
  const int r  = f / 589824;
  const int n  = nt * 16 + (l & 15);
  const int kk = q * 32 + ((l >> 4) << 3) + j;
  const int c  = kk & 255, k = kk >> 8;
  wph[f] = (unsigned short)f2bf_bits(w[((r * 256 + n) * 256 + c) * 9 + k]);
}

// offw[r][18][256][3][3] -> owph[r][q=72][nt=2][lane=64][j=8] (n>=18 -> 0)
__global__ __launch_bounds__(256) void offwpack_kernel(
    const float* __restrict__ offw, unsigned short* __restrict__ owph) {
  const int f = blockIdx.x * 256 + threadIdx.x;   // < 294,912
  const int j  = f & 7;
  const int l  = (f >> 3) & 63;
  const int nt = (f >> 9) & 1;
  const int q  = (f >> 10) % 72;
  const int r  = f / 73728;
  const int n  = nt * 16 + (l & 15);
  const int kk = q * 32 + ((l >> 4) << 3) + j;
  const int c  = kk & 255, k = kk >> 8;
  const float v = (n < 18) ? offw[((r * 18 + n) * 256 + c) * 9 + k] : 0.f;
  owph[f] = (unsigned short)f2bf_bits(v);
}

// ---------------------------------------------------------------------------
// x [4][256][4096] fp32 -> xT [4][4096][256] bf16-hi (transpose + cast)
__global__ __launch_bounds__(256) void xpose_kernel(
    const float* __restrict__ x, unsigned short* __restrict__ xh) {
  const int p0 = blockIdx.x * 64;     // pos tile
  const int c0 = blockIdx.y * 64;     // channel tile
  const int b  = blockIdx.z;
  __shared__ float sT[64][65];
  const int t = threadIdx.x;
  const int pj = t & 63, ci0 = (t >> 6) * 16;
  const float* __restrict__ xb = x + ((size_t)(b * 256 + c0)) * HW + p0;
#pragma unroll
  for (int u = 0; u < 16; ++u)
    sT[ci0 + u][pj] = xb[(size_t)(ci0 + u) * HW + pj];
  __syncthreads();
  const int pr = t >> 2, cs = (t & 3) * 16;
  u16x8 va, vb;
#pragma unroll
  for (int u = 0; u < 8; ++u) va[u] = (unsigned short)f2bf_bits(sT[cs + u][pr]);
#pragma unroll
  for (int u = 0; u < 8; ++u) vb[u] = (unsigned short)f2bf_bits(sT[cs + 8 + u][pr]);
  const size_t o = ((size_t)b * HW + p0 + pr) * 256 + c0 + cs;
  *(u16x8*)(xh + o) = va;
  *(u16x8*)(xh + o + 8) = vb;
}

// ---------------------------------------------------------------------------
// FUSED: offset-conv head + bilinear-sample + bf16 MFMA GEMM + ReLU.
// Block: M=64 (full row h), N=256, 1024 threads = 16 waves, grid 256
// (1 block/CU). Head: (mtO,ntO,kv)=(wv&3,(wv>>2)&1,wv>>3).
// Main loop waves: kv = wv>>3 (chunk parity), wmh = (wv>>2)&1 (32-row
// half), wng = wv&3 (64-col group). 2-chunk supers into ONE 8KB buffer
// (even chunk -> "hi" slots, odd chunk -> ^64 slots); kv0 waves read rb,
// kv1 read rb^64. Single-bf16 A: 8 MFMAs + 2 ds_read_b128/wave/super.
__global__ __launch_bounds__(1024, 4) void deform_mfma(
    const unsigned short* __restrict__ xh,   // [4][4096][256] bf16-hi plane
    const unsigned short* __restrict__ owh,  // offset B frags, this layer
    const float* __restrict__ offb,          // bias[18], this layer
    const unsigned short* __restrict__ wph,  // [72][16][64][8] this layer
    unsigned short* __restrict__ yth,        // next plane (layers 0-2)
    float* __restrict__ outf) {              // fp32 NCHW out (layer 3)
  const int gid = blockIdx.x;                  // 0..255
  const int b = (gid & 7) >> 1;                // 2 XCDs per batch image
  const int h = ((gid >> 3) << 1) | (gid & 1);     // full row 0..63
  const int t = threadIdx.x, lane = t & 63, wv = t >> 6;   // 16 waves
  const int frow = lane & 15, quad = lane >> 4;
  const int sm = t >> 4, cg = t & 15;          // staging: row 0..63, pair 0..15

  __shared__ __align__(16) unsigned char smem[39424];
  float* s_cw = (float*)smem;                  // [9][4][64] = 9216 B
  int*   s_ci = (int*)(smem + 9216);           // [9][4][64] = 9216 B
  unsigned char* sAb = smem + 18432;           // 2 sub-bufs x 8192 B
  float* s_off = (float*)(smem + 34816);       // [18][64] = 4608 B

  // ======== offset-conv head: this block's 18x64 offsets -> s_off ========
  {
    const int kv = wv >> 3, ntO = (wv >> 2) & 1, mtO = wv & 3;
    const int mO = mtO * 16 + frow;            // w coordinate of A row
    f32x4 aoc = {0.f, 0.f, 0.f, 0.f};
    const u16x8 z8 = {};
    const size_t xb = (size_t)b * HW;
    const u16x8* __restrict__ owp = (const u16x8*)owh;

#define OHLOAD(k, p, A, Bv)                                                 \
  {                                                                         \
    const int ky = (k) / 3 - 1, kx = (k) % 3 - 1;                           \
    const int hy = h + ky;                                                  \
    const int hyc = hy < 0 ? 0 : (hy > 63 ? 63 : hy);                       \
    const int mx = mO + kx;                                                 \
    const bool v = ((unsigned)hy < 64u) && ((unsigned)mx < 64u);            \
    const int cpx = mx < 0 ? 0 : (mx > 63 ? 63 : mx);                       \
    const size_t abase = (xb + (size_t)(hyc * 64 + cpx)) * 256              \
                         + quad * 8 + kv * 128 + (p) * 64;                  \
    _Pragma("unroll") for (int j = 0; j < 2; ++j) {                         \
      A[j] = *(const u16x8*)(xh + abase + j * 32);                          \
      if (!v) A[j] = z8;                                                    \
    }                                                                       \
    _Pragma("unroll") for (int j = 0; j < 2; ++j)                           \
      Bv[j] = owp[(((k) * 8 + kv * 4 + (p) * 2 + j) * 2 + ntO) * 64 + lane];\
  }

#define OHMFMA(A, Bv)                                                       \
  _Pragma("unroll") for (int j = 0; j < 2; ++j)                             \
    aoc = __builtin_amdgcn_mfma_f32_16x16x32_bf16(                          \
        __builtin_bit_cast(bf16x8, A[j]), __builtin_bit_cast(bf16x8, Bv[j]),\
        aoc, 0, 0, 0);

    u16x8 A0[2], Bv0[2], A1[2], Bv1[2];
    OHLOAD(0, 0, A0, Bv0)
    OHLOAD(0, 1, A1, Bv1)
    OHMFMA(A0, Bv0) OHLOAD(1, 0, A0, Bv0)
    OHMFMA(A1, Bv1) OHLOAD(1, 1, A1, Bv1)
    OHMFMA(A0, Bv0) OHLOAD(2, 0, A0, Bv0)
    OHMFMA(A1, Bv1) OHLOAD(2, 1, A1, Bv1)
    OHMFMA(A0, Bv0) OHLOAD(3, 0, A0, Bv0)
    OHMFMA(A1, Bv1) OHLOAD(3, 1, A1, Bv1)
    OHMFMA(A0, Bv0) OHLOAD(4, 0, A0, Bv0)
    OHMFMA(A1, Bv1) OHLOAD(4, 1, A1, Bv1)
    OHMFMA(A0, Bv0) OHLOAD(5, 0, A0, Bv0)
    OHMFMA(A1, Bv1) OHLOAD(5, 1, A1, Bv1)
    OHMFMA(A0, Bv0) OHLOAD(6, 0, A0, Bv0)
    OHMFMA(A1, Bv1) OHLOAD(6, 1, A1, Bv1)
    OHMFMA(A0, Bv0) OHLOAD(7, 0, A0, Bv0)
    OHMFMA(A1, Bv1) OHLOAD(7, 1, A1, Bv1)
    OHMFMA(A0, Bv0) OHLOAD(8, 0, A0, Bv0)
    OHMFMA(A1, Bv1) OHLOAD(8, 1, A1, Bv1)
    OHMFMA(A0, Bv0)
    OHMFMA(A1, Bv1)
#undef OHLOAD
#undef OHMFMA

    f32x4* redp = (f32x4*)(smem + 18432);      // transient, pre-main-loop
    if (kv == 1) redp[(mtO * 2 + ntO) * 64 + lane] = aoc;
    __syncthreads();
    if (kv == 0) {
      const f32x4 o = redp[(mtO * 2 + ntO) * 64 + lane];
      aoc[0] += o[0]; aoc[1] += o[1]; aoc[2] += o[2]; aoc[3] += o[3];
      const int oc = ntO * 16 + frow;          // C/D: col = lane&15 -> n
      if (oc < 18) {
        const float bv = offb[oc];
        const int mb = mtO * 16 + quad * 4;    // C/D row = (lane>>4)*4 + r
#pragma unroll
        for (int r = 0; r < 4; ++r) s_off[oc * 64 + mb + r] = aoc[r] + bv;
      }
    }
    __syncthreads();
  }

  // ======== phase 0: per (k, m) bilinear setup from s_off ========
  if (t < 576) {
    const int k = t >> 6, m = t & 63;
    const int ky = k / 3 - 1, kx = k % 3 - 1;
    const float dy = s_off[(2 * k) * 64 + m];
    const float dx = s_off[(2 * k + 1) * 64 + m];
    const float py = (float)(h + ky) + dy;
    const float px = (float)(m + kx) + dx;
    const float y0f = floorf(py), x0f = floorf(px);
    const float wy = py - y0f, wx = px - x0f;
    const int y0 = (int)y0f, x0 = (int)x0f;
#pragma unroll
    for (int j = 0; j < 4; ++j) {
      const int yi = y0 + (j >> 1), xi = x0 + (j & 1);
      const bool v = (yi >= 0) && (yi < 64) && (xi >= 0) && (xi < 64);
      const float wgt = ((j >> 1) ? wy : 1.f - wy) * ((j & 1) ? wx : 1.f - wx);
      s_cw[(k * 4 + j) * 64 + m] = v ? wgt : 0.f;
      const int yc = yi < 0 ? 0 : (yi > 63 ? 63 : yi);
      const int xc = xi < 0 ? 0 : (xi > 63 ? 63 : xi);
      s_ci[(k * 4 + j) * 64 + m] = yc * 64 + xc;
    }
  }
  __syncthreads();

  f32x4 acc[2][4];                             // 2 m-tiles x 4 n-tiles
#pragma unroll
  for (int mt = 0; mt < 2; ++mt)
#pragma unroll
    for (int nt = 0; nt < 4; ++nt) acc[mt][nt] = (f32x4){0.f, 0.f, 0.f, 0.f};

  const char* __restrict__ xbc = (const char*)(xh + (size_t)b * HW * 256);
  const u16x8* __restrict__ wp = (const u16x8*)wph;
  const int kv  = wv >> 3;                     // chunk parity (0=even,1=odd)
  const int wmh = (wv >> 2) & 1;               // m-half (32 rows)
  const int wng = wv & 3;                      // n-group (4 n-tiles)
  const int bfo = wng * 4;                     // wave's n-tile base

  // XOR-swizzled staging addresses (loop-invariant, per 8KB sub-buffer).
  const int gs = ((sm & 3) << 1) | ((sm >> 2) & 1);
  const int wbA = sm * 128 + ((((cg >> 2) ^ gs)) << 4) + (cg & 3) * 4;  // even
  const int wbL = wbA ^ 64;                                            // odd
  const int gr = ((frow & 3) << 1) | ((frow >> 2) & 1);
  // A-frag read base: kv selects even (rb) / odd (rb^64) chunk slots.
  const int rbK = ((wmh * 32 + frow) * 128 + ((quad ^ gr) << 4)) ^ (kv << 6);

  unsigned int G0A[4], G1A[4], G0B[4], G1B[4];
  u16x8 Bc[4];
  float cwrC[4], cwrN[4];
  int cibC[4], cibN[4];
#pragma unroll
  for (int j = 0; j < 4; ++j) {   // tap 0 staging params (byte offsets)
    cwrC[j] = s_cw[j * 64 + sm];
    cibC[j] = s_ci[j * 64 + sm] * 512;
  }
#pragma unroll
  for (int j = 0; j < 4; ++j)     // super 0: chunks 0,1
    G0A[j] = *(const unsigned int*)(xbc + cibC[j] + cg * 4);
#pragma unroll
  for (int j = 0; j < 4; ++j)
    G1A[j] = *(const unsigned int*)(xbc + cibC[j] + 64 + cg * 4);
#pragma unroll
  for (int j = 0; j < 4; ++j)     // super 1: chunks 2,3
    G0B[j] = *(const unsigned int*)(xbc + cibC[j] + 128 + cg * 4);
#pragma unroll
  for (int j = 0; j < 4; ++j)
    G1B[j] = *(const unsigned int*)(xbc + cibC[j] + 192 + cg * 4);
#pragma unroll
  for (int i = 0; i < 4; ++i)     // B frags of this wave's first chunk (=kv)
    Bc[i] = wp[(kv * 16 + bfo + i) * 64 + lane];

// Combine 8 bf16 samples, store 2 packed bf16 (hi only) at WB of buffer BB.
#define COMBINE_STORE(Gx, BB, WB)                                           \
  {                                                                         \
    float s0 = cwrC[0] * __uint_as_float(Gx[0] << 16);                      \
    float s1 = cwrC[0] * __uint_as_float(Gx[0] & 0xffff0000u);              \
    s0 = fmaf(cwrC[1], __uint_as_float(Gx[1] << 16), s0);                   \
    s1 = fmaf(cwrC[1], __uint_as_float(Gx[1] & 0xffff0000u), s1);           \
    s0 = fmaf(cwrC[2], __uint_as_float(Gx[2] << 16), s0);                   \
    s1 = fmaf(cwrC[2], __uint_as_float(Gx[2] & 0xffff0000u), s1);           \
    s0 = fmaf(cwrC[3], __uint_as_float(Gx[3] << 16), s0);                   \
    s1 = fmaf(cwrC[3], __uint_as_float(Gx[3] & 0xffff0000u), s1);           \
    const __bf16 hb0 = (__bf16)s0, hb1 = (__bf16)s1;                        \
    const unsigned int hv =                                                 \
        (unsigned int)__builtin_bit_cast(unsigned short, hb0) |             \
        ((unsigned int)__builtin_bit_cast(unsigned short, hb1) << 16);      \
    *(unsigned int*)(sAb + (BB) + (WB)) = hv;                               \
  }

// One consumed chunk per wave per super: 2 m-tiles x 4 n-tiles, single-bf16.
#define MFMA_BODY(PBv)                                                      \
  {                                                                         \
    bf16x8 ah[2];                                                           \
    ah[0] = __builtin_bit_cast(bf16x8, *(const u16x8*)(sAb + (PBv) + rbK)); \
    ah[1] = __builtin_bit_cast(                                             \
        bf16x8, *(const u16x8*)(sAb + (PBv) + rbK + 2048));                 \
    __builtin_amdgcn_s_setprio(1);                                          \
    _Pragma("unroll") for (int nt = 0; nt < 4; ++nt) {                      \
      const bf16x8 bv = __builtin_bit_cast(bf16x8, Bc[nt]);                 \
      _Pragma("unroll") for (int mt = 0; mt < 2; ++mt) {                    \
        acc[mt][nt] = __builtin_amdgcn_mfma_f32_16x16x32_bf16(              \
            ah[mt], bv, acc[mt][nt], 0, 0, 0);                              \
      }                                                                     \
    }                                                                       \
    __builtin_amdgcn_s_setprio(0);                                          \
  }

#define BADV(cn)                                                            \
  {                                                                         \
    _Pragma("unroll") for (int i = 0; i < 4; ++i)                           \
      Bc[i] = wp[((cn) * 16 + bfo + i) * 64 + lane];                        \
  }

  for (int k9 = 0; k9 < 9; ++k9) {
    const bool tapN = (k9 < 8);
    // ---- s=0: buffer 0, regs A; prefetch this-tap chunks 4,5 ----
    COMBINE_STORE(G0A, 0, wbA)
    COMBINE_STORE(G1A, 0, wbL)
    wg_barrier_lds();
#pragma unroll
    for (int j = 0; j < 4; ++j)
      G0A[j] = *(const unsigned int*)(xbc + cibC[j] + 256 + cg * 4);
#pragma unroll
    for (int j = 0; j < 4; ++j)
      G1A[j] = *(const unsigned int*)(xbc + cibC[j] + 320 + cg * 4);
    MFMA_BODY(0)
    BADV(k9 * 8 + 2 + kv)
    // ---- s=1: buffer 8192, regs B; fetch next-tap params;
    //           prefetch this-tap chunks 6,7 ----
    COMBINE_STORE(G0B, 8192, wbA)
    COMBINE_STORE(G1B, 8192, wbL)
    wg_barrier_lds();
    if (tapN) {
#pragma unroll
      for (int j = 0; j < 4; ++j) {
        cwrN[j] = s_cw[((k9 + 1) * 4 + j) * 64 + sm];
        cibN[j] = s_ci[((k9 + 1) * 4 + j) * 64 + sm] * 512;
      }
    }
#pragma unroll
    for (int j = 0; j < 4; ++j)
      G0B[j] = *(const unsigned int*)(xbc + cibC[j] + 384 + cg * 4);
#pragma unroll
    for (int j = 0; j < 4; ++j)
      G1B[j] = *(const unsigned int*)(xbc + cibC[j] + 448 + cg * 4);
    MFMA_BODY(8192)
    BADV(k9 * 8 + 4 + kv)
    // ---- s=2: buffer 0, regs A; prefetch next-tap chunks 0,1 ----
    COMBINE_STORE(G0A, 0, wbA)
    COMBINE_STORE(G1A, 0, wbL)
    wg_barrier_lds();
    if (tapN) {
#pragma unroll
      for (int j = 0; j < 4; ++j)
        G0A[j] = *(const unsigned int*)(xbc + cibN[j] + cg * 4);
#pragma unroll
      for (int j = 0; j < 4; ++j)
        G1A[j] = *(const unsigned int*)(xbc + cibN[j] + 64 + cg * 4);
    }
    MFMA_BODY(0)
    BADV(k9 * 8 + 6 + kv)
    // ---- s=3: buffer 8192, regs B; prefetch next-tap chunks 2,3 ----
    COMBINE_STORE(G0B, 8192, wbA)
    COMBINE_STORE(G1B, 8192, wbL)
    wg_barrier_lds();
    if (tapN) {
#pragma unroll
      for (int j = 0; j < 4; ++j)
        G0B[j] = *(const unsigned int*)(xbc + cibN[j] + 128 + cg * 4);
#pragma unroll
      for (int j = 0; j < 4; ++j)
        G1B[j] = *(const unsigned int*)(xbc + cibN[j] + 192 + cg * 4);
    }
    MFMA_BODY(8192)
    if (tapN) {
      BADV(k9 * 8 + 8 + kv)
#pragma unroll
      for (int j = 0; j < 4; ++j) { cwrC[j] = cwrN[j]; cibC[j] = cibN[j]; }
    }
  }
#undef COMBINE_STORE
#undef MFMA_BODY
#undef BADV

  // ======== cross-kv accumulator reduction (kv1 -> kv0), 2 phases ========
  __syncthreads();   // all K-loop LDS traffic done before smem reuse
  {
    float* redb = (float*)smem;                // 8 waves x 64 lanes x 16 f
    const int rbase = ((wv & 7) * 64 + lane) * 16;
#pragma unroll
    for (int ph = 0; ph < 2; ++ph) {
      if (kv == 1) {
#pragma unroll
        for (int mt = 0; mt < 2; ++mt)
#pragma unroll
          for (int q2 = 0; q2 < 2; ++q2)
            *(f32x4*)&redb[rbase + (mt * 2 + q2) * 4] = acc[mt][ph * 2 + q2];
      }
      __syncthreads();
      if (kv == 0) {
#pragma unroll
        for (int mt = 0; mt < 2; ++mt)
#pragma unroll
          for (int q2 = 0; q2 < 2; ++q2) {
            const f32x4 o = *(const f32x4*)&redb[rbase + (mt * 2 + q2) * 4];
            acc[mt][ph * 2 + q2][0] += o[0];
            acc[mt][ph * 2 + q2][1] += o[1];
            acc[mt][ph * 2 + q2][2] += o[2];
            acc[mt][ph * 2 + q2][3] += o[3];
          }
      }
      __syncthreads();
    }
  }

  if (outf) {
    // final layer: ReLU + direct fp32 NCHW scatter (kv0 waves only)
    if (kv == 0) {
#pragma unroll
      for (int mt = 0; mt < 2; ++mt)
#pragma unroll
        for (int nt = 0; nt < 4; ++nt) {
          const int n = wng * 64 + nt * 16 + frow;
          const int pos = h * 64 + wmh * 32 + mt * 16 + quad * 4;
          float4 vv;
          vv.x = fmaxf(acc[mt][nt][0], 0.f);
          vv.y = fmaxf(acc[mt][nt][1], 0.f);
          vv.z = fmaxf(acc[mt][nt][2], 0.f);
          vv.w = fmaxf(acc[mt][nt][3], 0.f);
          *(float4*)&outf[(size_t)(b * 256 + n) * HW + pos] = vv;
        }
    }
  } else {
    // layers 0-2: ReLU + bf16-hi transposed plane, kv0 waves via LDS slice.
    // Per kv0 wave: 32 rows x 64 cols through sW [32][72] (no 2^k alias).
    unsigned short* sW = (unsigned short*)(smem + (wv & 7) * 4608);
    if (kv == 0) {
#pragma unroll
      for (int mt = 0; mt < 2; ++mt)
#pragma unroll
        for (int nt = 0; nt < 4; ++nt)
#pragma unroll
          for (int r = 0; r < 4; ++r)
            sW[(mt * 16 + quad * 4 + r) * 72 + nt * 16 + frow] =
                (unsigned short)f2bf_bits(fmaxf(acc[mt][nt][r], 0.f));
    }
    __syncthreads();
    if (kv == 0) {
      const int rowl = lane & 31, colh = lane >> 5;  // 32 rows x 2 col-chunks
      const int pos = h * 64 + wmh * 32 + rowl;
      unsigned short* __restrict__ yp =
          yth + ((size_t)b * HW + pos) * 256 + wng * 64 + colh * 32;
#pragma unroll
      for (int g = 0; g < 4; ++g)
        *(u16x8*)(yp + g * 8) = *(const u16x8*)&sW[rowl * 72 + colh * 32 + g * 8];
    }
  }
}

extern "C" void kernel_launch(void* const* d_in, const int* in_sizes, int n_in,
                              void* d_out, int out_size, void* d_ws, size_t ws_size,
                              hipStream_t stream) {
  const float* x0   = (const float*)d_in[0];  // [4][256][64][64]
  const float* offw = (const float*)d_in[1];  // [4][18][256][3][3]
  const float* offb = (const float*)d_in[2];  // [4][18]
  const float* w    = (const float*)d_in[3];  // [4][256][256][3][3]
  float* out = (float*)d_out;                 // [4][256][64][64]
  float* ws  = (float*)d_ws;

  unsigned short* wph  = (unsigned short*)(ws + 294912);    // 2,359,296 ushort
  unsigned short* owph = wph + 2359296;                     //   294,912 ushort
  unsigned short* xTA  = owph + 294912;                     // 4,194,304 ushort
  unsigned short* xTB  = xTA + 4194304;                     // 4,194,304 ushort

  wpack_kernel<<<9216, 256, 0, stream>>>(w, wph);
  offwpack_kernel<<<1152, 256, 0, stream>>>(offw, owph);
  xpose_kernel<<<dim3(64, 4, 4), 256, 0, stream>>>(x0, xTA);

  unsigned short* pin = xTA;
  unsigned short* pout = xTB;
  for (int r = 0; r < 4; ++r) {
    deform_mfma<<<256, 1024, 0, stream>>>(pin, owph + r * 73728,
                                          offb + r * 18,
                                          wph + (size_t)r * 589824,
                                          (r < 3) ? pout : nullptr,
                                          (r < 3) ? nullptr : out);
    unsigned short* tmp = pin; pin = pout; pout = tmp;
  }
}